// Round 5
// baseline (651.391 us; speedup 1.0000x reference)
//
#include <hip/hip_runtime.h>
#include <hip/hip_bf16.h>
#include <stdint.h>

typedef short short8  __attribute__((ext_vector_type(8)));
typedef float f32x4   __attribute__((ext_vector_type(4)));
typedef float f32x16  __attribute__((ext_vector_type(16)));

typedef __attribute__((address_space(1))) uint32_t u32_g;
typedef __attribute__((address_space(3))) uint32_t u32_l;

#define BM 128
#define BN 128
#define BK 64

// async global->LDS, 16B per lane; LDS dest = wave-uniform base + lane*16.
__device__ __forceinline__ void gld_lds16(const void* g, const void* l) {
  __builtin_amdgcn_global_load_lds((u32_g*)(uintptr_t)g, (u32_l*)(uintptr_t)l, 16, 0, 0);
}

// ---- aux bodies (run as extra blocks piggybacked on GEMM dispatches) -------

// weight transpose + fp32->bf16: src[K,N] -> dst[n][k], rows n>=N zeroed.
// Uses caller-provided LDS (>= 32*33 bf16).
__device__ __forceinline__ void aux_transpose(
    __hip_bfloat16 (*t)[33],
    const float* __restrict__ src, __hip_bfloat16* __restrict__ dst,
    int K, int N, int nbx, int b, int tid)
{
  const int bx = b % nbx, by = b / nbx;
  const int n0 = bx * 32, k0 = by * 32;
  const int tx = tid & 31, ty = tid >> 5;
  const __hip_bfloat16 zero = __float2bfloat16(0.f);
#pragma unroll
  for (int r = 0; r < 32; r += 8) {
    int k = k0 + ty + r, n = n0 + tx;
    t[ty + r][tx] = (n < N) ? __float2bfloat16(src[(size_t)k * N + n]) : zero;
  }
  __syncthreads();
#pragma unroll
  for (int r = 0; r < 32; r += 8) {
    int n = n0 + ty + r;
    dst[(size_t)n * K + k0 + tx] = t[tx][ty + r];
  }
}

// zero one lower-triangle (r,c) slab of 8192 floats (c < r).
__device__ __forceinline__ void aux_zlo(float* __restrict__ out, int p, int tid)
{
  int r = (int)((1.0f + sqrtf(1.0f + 8.0f * (float)p)) * 0.5f);
  while (r * (r - 1) / 2 > p) --r;
  while ((r + 1) * r / 2 <= p) ++r;
  int c = p - r * (r - 1) / 2;
  float* dstp = out + (size_t)(r * 64 + c) * 8192;
  f32x4 z = (f32x4){0.f, 0.f, 0.f, 0.f};
#pragma unroll
  for (int i = 0; i < 8; ++i)
    *reinterpret_cast<f32x4*>(dstp + i * 1024 + tid * 4) = z;
}

// ---------------------------------------------------------------------------
// Hidden-layer GEMM (32x32x16 MFMA) + piggybacked aux blocks.
// GEMM blocks: bid < 1024 (dispatched first -> compute path starts at t=0).
// Aux blocks:  [1024, 1024+tblocks)          transpose tsrc->tdst
//              [1024+tblocks, +zcount)       zero lower-tri slabs zstart+..
// C/D layout (m74/m101): col = lane&31, row = (reg&3)+8*(reg>>2)+4*(lane>>5)
// -> 64B-aligned sector-clean bf16 stores (WRITE_SIZE 36.5MB ~= ideal, R3).
// ---------------------------------------------------------------------------
__global__ __launch_bounds__(256) void gemm32_k(
    const __hip_bfloat16* __restrict__ A,
    const __hip_bfloat16* __restrict__ BT,
    const float* __restrict__ bias,
    __hip_bfloat16* __restrict__ C,
    int K,
    const float* __restrict__ tsrc, __hip_bfloat16* __restrict__ tdst,
    int tK, int tN, int tnbx, int tblocks,
    float* __restrict__ zout, int zstart, int zcount)
{
  __shared__ __attribute__((aligned(16))) __hip_bfloat16 As[BM * BK];
  __shared__ __attribute__((aligned(16))) __hip_bfloat16 Bs[BN * BK];

  const int tid = threadIdx.x;
  const int bid = blockIdx.x;

  if (bid >= 1024) {
    int a = bid - 1024;
    if (a < tblocks) {
      aux_transpose(reinterpret_cast<__hip_bfloat16(*)[33]>(As),
                    tsrc, tdst, tK, tN, tnbx, a, tid);
    } else {
      aux_zlo(zout, zstart + (a - tblocks), tid);
    }
    return;
  }

  const int lane = tid & 63;
  const int l31  = lane & 31;
  const int half = lane >> 5;
  const int wave = tid >> 6;
  const int wm   = (wave >> 1) << 6;
  const int wn   = (wave & 1) << 6;

  const int bm = (bid & 63) * BM;
  const int bn = (bid >> 6) * BN;

  // Staging: XOR chunk swizzle on the global side keeps LDS wave-contiguous
  // (global_load_lds constraint) while fragment reads spread across banks.
  const __hip_bfloat16* ag[4];
  const __hip_bfloat16* bg[4];
  uint32_t lofs[4];
#pragma unroll
  for (int c = 0; c < 4; ++c) {
    int ci   = tid + 256 * c;
    int row  = ci >> 3;
    int chk  = ci & 7;
    int gchk = chk ^ (row & 7);
    ag[c]   = A  + (size_t)(bm + row) * K + gchk * 8;
    bg[c]   = BT + (size_t)(bn + row) * K + gchk * 8;
    lofs[c] = (uint32_t)ci * 16u;
  }

  f32x16 acc[2][2];
#pragma unroll
  for (int i = 0; i < 2; ++i)
#pragma unroll
    for (int j = 0; j < 2; ++j)
      acc[i][j] = (f32x16)(0.f);

  const int nk = K >> 6;
  for (int kt = 0; kt < nk; ++kt) {
#pragma unroll
    for (int c = 0; c < 4; ++c) {
      gld_lds16(ag[c], (const char*)As + lofs[c]);
      gld_lds16(bg[c], (const char*)Bs + lofs[c]);
      ag[c] += BK;
      bg[c] += BK;
    }
    __syncthreads();
#pragma unroll
    for (int kk = 0; kk < 4; ++kk) {
      short8 af[2], bf[2];
      const int cf = kk * 2 + half;
#pragma unroll
      for (int t = 0; t < 2; ++t) {
        int m  = wm + t * 32 + l31;
        af[t]  = *(const short8*)(As + m * BK + (cf ^ (m & 7)) * 8);
        int n  = wn + t * 32 + l31;
        bf[t]  = *(const short8*)(Bs + n * BK + (cf ^ (n & 7)) * 8);
      }
#pragma unroll
      for (int ti = 0; ti < 2; ++ti)
#pragma unroll
        for (int tj = 0; tj < 2; ++tj)
          acc[ti][tj] = __builtin_amdgcn_mfma_f32_32x32x16_bf16(af[ti], bf[tj], acc[ti][tj], 0, 0, 0);
    }
    __syncthreads();
  }

#pragma unroll
  for (int tj = 0; tj < 2; ++tj) {
    int   n  = bn + wn + tj * 32 + l31;
    float bv = bias[n];
#pragma unroll
    for (int ti = 0; ti < 2; ++ti) {
      int base = bm + wm + ti * 32 + 4 * half;
#pragma unroll
      for (int reg = 0; reg < 16; ++reg) {
        int m   = base + (reg & 3) + 8 * (reg >> 2);
        float v = acc[ti][tj][reg] + bv;
        v = (v > 0.f) ? v : 0.01f * v;
        C[(size_t)m * 2048 + n] = __float2bfloat16(v);
      }
    }
  }
}

// ---------------------------------------------------------------------------
// Final GEMM (16x16x32): y = A @ W3T^T + b3, diag-abs + triangle scatter as
// fp32: out[(r*64+c)*8192 + m], 16B f32x4 stores (64B aligned segments).
// ---------------------------------------------------------------------------
__global__ __launch_bounds__(256) void gemm16f_k(
    const __hip_bfloat16* __restrict__ A,
    const __hip_bfloat16* __restrict__ BT,
    const float* __restrict__ bias,
    float* __restrict__ Cf,
    const int* __restrict__ tbl,
    int K, int Nreal)
{
  __shared__ __attribute__((aligned(16))) __hip_bfloat16 As[BM * BK];
  __shared__ __attribute__((aligned(16))) __hip_bfloat16 Bs[BN * BK];

  const int tid  = threadIdx.x;
  const int lane = tid & 63;
  const int l15  = lane & 15;
  const int quad = lane >> 4;
  const int wave = tid >> 6;
  const int wm   = (wave >> 1) << 6;
  const int wn   = (wave & 1) << 6;

  const int bid = blockIdx.x;
  const int bm = (bid & 63) * BM;
  const int bn = (bid >> 6) * BN;

  const __hip_bfloat16* ag[4];
  const __hip_bfloat16* bg[4];
  uint32_t lofs[4];
#pragma unroll
  for (int c = 0; c < 4; ++c) {
    int ci   = tid + 256 * c;
    int row  = ci >> 3;
    int chk  = ci & 7;
    int gchk = chk ^ (row & 7);
    ag[c]   = A  + (size_t)(bm + row) * K + gchk * 8;
    bg[c]   = BT + (size_t)(bn + row) * K + gchk * 8;
    lofs[c] = (uint32_t)ci * 16u;
  }

  f32x4 acc[4][4];
#pragma unroll
  for (int i = 0; i < 4; ++i)
#pragma unroll
    for (int j = 0; j < 4; ++j)
      acc[i][j] = (f32x4){0.f, 0.f, 0.f, 0.f};

  const int nk = K >> 6;
  for (int kt = 0; kt < nk; ++kt) {
#pragma unroll
    for (int c = 0; c < 4; ++c) {
      gld_lds16(ag[c], (const char*)As + lofs[c]);
      gld_lds16(bg[c], (const char*)Bs + lofs[c]);
      ag[c] += BK;
      bg[c] += BK;
    }
    __syncthreads();
#pragma unroll
    for (int ks = 0; ks < 2; ++ks) {
      short8 af[4], bf[4];
      const int cf = ks * 4 + quad;
#pragma unroll
      for (int i = 0; i < 4; ++i) {
        int m  = wm + i * 16 + l15;
        af[i]  = *(const short8*)(As + m * BK + ((cf ^ (m & 7)) * 8));
      }
#pragma unroll
      for (int j = 0; j < 4; ++j) {
        int n  = wn + j * 16 + l15;
        bf[j]  = *(const short8*)(Bs + n * BK + ((cf ^ (n & 7)) * 8));
      }
#pragma unroll
      for (int i = 0; i < 4; ++i)
#pragma unroll
        for (int j = 0; j < 4; ++j)
          acc[i][j] = __builtin_amdgcn_mfma_f32_16x16x32_bf16(af[i], bf[j], acc[i][j], 0, 0, 0);
    }
    __syncthreads();
  }

#pragma unroll
  for (int j = 0; j < 4; ++j) {
    int n = bn + wn + j * 16 + l15;
    if (n < Nreal) {
      float bv   = bias[n];
      int  code  = tbl[n];
      int  dst   = code & 4095;
      bool diag  = (code & 4096) != 0;
#pragma unroll
      for (int i = 0; i < 4; ++i) {
        int m0 = bm + wm + i * 16 + quad * 4;
        f32x4 pk;
#pragma unroll
        for (int r = 0; r < 4; ++r) {
          float v = acc[i][j][r] + bv;
          if (diag) v = fabsf(v);
          pk[r] = v;
        }
        *reinterpret_cast<f32x4*>(Cf + (size_t)dst * 8192 + m0) = pk;
      }
    }
  }
}

// ---------------------------------------------------------------------------
// Minimal prep: only what GEMM1 needs (x->bf16, W1T) + scatter table.
//   [0, 8192)        cvt x (8192x1024, 4 elem/thread)
//   [8192, 10240)    W1 transpose (2048 blocks)
//   [10240, 10249)   scatter table
// ---------------------------------------------------------------------------
__global__ __launch_bounds__(256) void prep_k(
    const float* __restrict__ x,  __hip_bfloat16* __restrict__ xb,
    const float* __restrict__ W1, __hip_bfloat16* __restrict__ W1T,
    int* __restrict__ tbl)
{
  __shared__ __hip_bfloat16 t[32][33];
  const int tid = threadIdx.x;
  int bid = blockIdx.x;

  if (bid < 8192) {
    int i = bid * 1024 + tid * 4;
    float4 v = *reinterpret_cast<const float4*>(x + i);
    union { unsigned short us[4]; uint2 v2; } pk;
    __hip_bfloat16 h;
    h = __float2bfloat16(v.x); pk.us[0] = *reinterpret_cast<unsigned short*>(&h);
    h = __float2bfloat16(v.y); pk.us[1] = *reinterpret_cast<unsigned short*>(&h);
    h = __float2bfloat16(v.z); pk.us[2] = *reinterpret_cast<unsigned short*>(&h);
    h = __float2bfloat16(v.w); pk.us[3] = *reinterpret_cast<unsigned short*>(&h);
    *reinterpret_cast<uint2*>(xb + i) = pk.v2;
    return;
  }
  bid -= 8192;

  if (bid < 2048) {
    aux_transpose(t, W1, W1T, 1024, 2048, 64, bid, tid);
    return;
  }
  bid -= 2048;

  int l = bid * 256 + tid;
  if (l < 2080) {
    int r = 0, s = 0;
    while (s + (64 - r) <= l) { s += 64 - r; ++r; }
    int c = 63 - (l - s);
    tbl[l] = (r * 64 + c) | ((r == c) ? 4096 : 0);
  }
}

extern "C" void kernel_launch(void* const* d_in, const int* in_sizes, int n_in,
                              void* d_out, int out_size, void* d_ws, size_t ws_size,
                              hipStream_t stream)
{
  const float* x   = (const float*)d_in[0];
  const float* W1  = (const float*)d_in[1];
  const float* b1  = (const float*)d_in[2];
  const float* W2  = (const float*)d_in[3];
  const float* b2  = (const float*)d_in[4];
  const float* W21 = (const float*)d_in[5];
  const float* b21 = (const float*)d_in[6];
  const float* W22 = (const float*)d_in[7];
  const float* b22 = (const float*)d_in[8];
  const float* W3  = (const float*)d_in[9];
  const float* b3  = (const float*)d_in[10];
  float* out = (float*)d_out;

  char* ws = (char*)d_ws;
  __hip_bfloat16* act0 = (__hip_bfloat16*)(ws);                         // 8192x2048 bf16
  __hip_bfloat16* act1 = (__hip_bfloat16*)(ws + ((size_t)32 << 20));    // 8192x2048 bf16
  __hip_bfloat16* xb   = act1;                                          // 8192x1024 (dead after GEMM1)
  __hip_bfloat16* W1T  = (__hip_bfloat16*)(ws + ((size_t)64 << 20));    // 2048x1024
  __hip_bfloat16* W2T  = (__hip_bfloat16*)(ws + ((size_t)68 << 20));    // 2048x2048
  __hip_bfloat16* W21T = (__hip_bfloat16*)(ws + ((size_t)76 << 20));    // 2048x2048
  __hip_bfloat16* W22T = (__hip_bfloat16*)(ws + ((size_t)84 << 20));    // 2048x2048
  __hip_bfloat16* W3T  = (__hip_bfloat16*)(ws + ((size_t)92 << 20));    // 2176x2048 (padded)
  int*            tbl  = (int*)(ws + ((size_t)101 << 20));              // 2080 ints

  // prep: xb + W1T + table (only GEMM1's prerequisites)
  prep_k<<<10249, 256, 0, stream>>>(x, xb, W1, W1T, tbl);

  // GEMM1 (K=1024) + piggyback: W2 transpose (4096 blocks) + zlo slabs [0,1000)
  gemm32_k<<<1024 + 4096 + 1000, 256, 0, stream>>>(
      xb, W1T, b1, act0, 1024,
      W2, W2T, 2048, 2048, 64, 4096, out, 0, 1000);

  // GEMM2 + piggyback: W21 transpose + zlo slabs [1000,2016)
  gemm32_k<<<1024 + 4096 + 1016, 256, 0, stream>>>(
      act0, W2T, b2, act1, 2048,
      W21, W21T, 2048, 2048, 64, 4096, out, 1000, 1016);

  // GEMM3 + piggyback: W22 transpose
  gemm32_k<<<1024 + 4096, 256, 0, stream>>>(
      act1, W21T, b21, act0, 2048,
      W22, W22T, 2048, 2048, 64, 4096, out, 0, 0);

  // GEMM4 + piggyback: W3 transpose (padded to 2176 rows, 68 x 64 blocks)
  gemm32_k<<<1024 + 4352, 256, 0, stream>>>(
      act0, W22T, b22, act1, 2048,
      W3, W3T, 2048, 2080, 68, 4352, out, 0, 0);

  // Final GEMM: scatter into out (upper triangle; lower zeroed by zlo)
  gemm16f_k<<<64 * 17, 256, 0, stream>>>(act1, W3T, b3, out, tbl, 2048, 2080);
}